// Round 3
// baseline (1132.247 us; speedup 1.0000x reference)
//
#include <hip/hip_runtime.h>

// ---------------- setup kernels ----------------

__global__ __launch_bounds__(256) void deg_kernel(const int* __restrict__ src,
                                                  const int* __restrict__ dst,
                                                  int* __restrict__ out_deg,
                                                  int* __restrict__ in_deg, int E) {
  int e = blockIdx.x * 256 + threadIdx.x;
  if (e < E) {
    atomicAdd(&out_deg[src[e]], 1);
    atomicAdd(&in_deg[dst[e]], 1);
  }
}

__global__ __launch_bounds__(256) void norm_kernel(const int* __restrict__ out_deg,
                                                   const int* __restrict__ in_deg,
                                                   float* __restrict__ out_norm,
                                                   float* __restrict__ in_norm, int N) {
  int n = blockIdx.x * 256 + threadIdx.x;
  if (n < N) {
    out_norm[n] = 1.0f / sqrtf((float)max(out_deg[n], 1));
    in_norm[n]  = 1.0f / sqrtf((float)max(in_deg[n], 1));
  }
}

// ---- parallel exclusive scan over N ints ----

__global__ __launch_bounds__(256) void scan_partial_kernel(const int* __restrict__ deg,
                                                           int* __restrict__ partial, int N) {
  __shared__ int ws[4];
  int tid = threadIdx.x, lane = tid & 63, wv = tid >> 6;
  int base = blockIdx.x * 1024;
  int v = 0;
#pragma unroll
  for (int k = 0; k < 4; ++k) {
    int i = base + tid + k * 256;
    if (i < N) v += deg[i];
  }
  for (int d = 32; d > 0; d >>= 1) v += __shfl_down(v, d, 64);
  if (lane == 0) ws[wv] = v;
  __syncthreads();
  if (tid == 0) partial[blockIdx.x] = ws[0] + ws[1] + ws[2] + ws[3];
}

__global__ __launch_bounds__(1024) void scan_partials_kernel(int* __restrict__ partial, int P) {
  __shared__ int wsum[16];
  int tid = threadIdx.x, lane = tid & 63, wv = tid >> 6;
  int v = (tid < P) ? partial[tid] : 0;
  int x = v;
  for (int d = 1; d < 64; d <<= 1) {
    int y = __shfl_up(x, d, 64);
    if (lane >= d) x += y;
  }
  if (lane == 63) wsum[wv] = x;
  __syncthreads();
  if (wv == 0 && lane < 16) {
    int y = wsum[lane];
    int z = y;
    for (int d = 1; d < 16; d <<= 1) {
      int q = __shfl_up(z, d, 64);
      if (lane >= d) z += q;
    }
    wsum[lane] = z - y;
  }
  __syncthreads();
  if (tid < P) partial[tid] = wsum[wv] + x - v;  // exclusive
}

__global__ __launch_bounds__(1024) void scan_apply_kernel(const int* __restrict__ deg,
                                                          const int* __restrict__ partial,
                                                          int* __restrict__ off, int N) {
  __shared__ int wsum[16];
  int tid = threadIdx.x, lane = tid & 63, wv = tid >> 6;
  int i = blockIdx.x * 1024 + tid;
  int v = (i < N) ? deg[i] : 0;
  int x = v;
  for (int d = 1; d < 64; d <<= 1) {
    int y = __shfl_up(x, d, 64);
    if (lane >= d) x += y;
  }
  if (lane == 63) wsum[wv] = x;
  __syncthreads();
  if (wv == 0 && lane < 16) {
    int y = wsum[lane];
    int z = y;
    for (int d = 1; d < 16; d <<= 1) {
      int q = __shfl_up(z, d, 64);
      if (lane >= d) z += q;
    }
    wsum[lane] = z - y;
  }
  __syncthreads();
  int excl = partial[blockIdx.x] + wsum[wv] + (x - v);
  if (i < N) off[i] = excl;
  if (i == N - 1) off[N] = excl + v;
}

__global__ __launch_bounds__(256) void scatter_kernel(const int* __restrict__ src,
                                                      const int* __restrict__ dst,
                                                      const int* __restrict__ in_off,
                                                      int* __restrict__ cursor,
                                                      int* __restrict__ csr_src, int E) {
  int e = blockIdx.x * 256 + threadIdx.x;
  if (e < E) {
    int d = dst[e];
    int p = atomicAdd(&cursor[d], 1);
    csr_src[in_off[d] + p] = src[e];
  }
}

// ---------------- graph-conv layer ----------------
// One wave per node. Software-pipelined gather: U edges per batch, all U (or
// 2U) float4 loads issued back-to-back into register arrays, next batch's
// indices prefetched before accumulation. __launch_bounds__(256,4) caps VGPR
// at 128 so the batch stays in registers (36 VGPRs last round = serialized).
template <int F_IN, int F_OUT, int RS, bool IT_LAYOUT, bool RELU, bool GNORM, bool SCALE_OUT, int U>
__global__ __launch_bounds__(256, 4) void layer_kernel(
    const float* __restrict__ h_in, const int* __restrict__ csr_src,
    const int* __restrict__ in_off, const float* __restrict__ out_norm,
    const float* __restrict__ in_norm, const float* __restrict__ W,
    const float* __restrict__ bias, float* __restrict__ h_out, int N) {
  constexpr int FT_IN = F_IN * 8;
  constexpr int NF4 = FT_IN / 4;  // 64 / 80 / 128
  constexpr int AGG = IT_LAYOUT ? FT_IN : RS * 8;
  __shared__ float agg_all[4][AGG];
  int lane = threadIdx.x & 63;
  int wave = threadIdx.x >> 6;
  float* agg = agg_all[wave];
  int n = blockIdx.x * 4 + wave;
  bool valid = (n < N);

  if (valid) {
    int e0 = in_off[n], e1 = in_off[n + 1];
    const float4* h4 = (const float4*)h_in;
    float4 a0 = make_float4(0.f, 0.f, 0.f, 0.f);
    float4 c0 = make_float4(0.f, 0.f, 0.f, 0.f);
    float4 a1 = make_float4(0.f, 0.f, 0.f, 0.f);
    float4 c1 = make_float4(0.f, 0.f, 0.f, 0.f);
    const bool hi = (NF4 >= 128) || (lane < NF4 - 64);  // second-slice predicate
    int j = e0;
    int nb = (e1 - e0) / U;
    if (nb > 0) {
      int s[U];
#pragma unroll
      for (int k = 0; k < U; ++k) s[k] = csr_src[j + k];
      for (int b = 0; b < nb; ++b) {
        // issue all data loads for this batch
        float4 v[U];
        float4 u[U];
#pragma unroll
        for (int k = 0; k < U; ++k) {
          const float4* p = h4 + (size_t)s[k] * NF4;
          v[k] = p[lane];
          if constexpr (NF4 > 64) {
            if (hi) u[k] = p[64 + lane];
          }
        }
        float w[U];
        if constexpr (GNORM) {
#pragma unroll
          for (int k = 0; k < U; ++k) w[k] = out_norm[s[k]];
        }
        j += U;
        // prefetch next batch's indices while loads are in flight
        if (b + 1 < nb) {
#pragma unroll
          for (int k = 0; k < U; ++k) s[k] = csr_src[j + k];
        }
        // accumulate (alternate accumulators to break dep chains)
#pragma unroll
        for (int k = 0; k < U; ++k) {
          float ws = 1.f;
          if constexpr (GNORM) ws = w[k];
          if (k & 1) {
            c0.x += v[k].x * ws; c0.y += v[k].y * ws; c0.z += v[k].z * ws; c0.w += v[k].w * ws;
          } else {
            a0.x += v[k].x * ws; a0.y += v[k].y * ws; a0.z += v[k].z * ws; a0.w += v[k].w * ws;
          }
          if constexpr (NF4 > 64) {
            if (hi) {
              if (k & 1) {
                c1.x += u[k].x * ws; c1.y += u[k].y * ws; c1.z += u[k].z * ws; c1.w += u[k].w * ws;
              } else {
                a1.x += u[k].x * ws; a1.y += u[k].y * ws; a1.z += u[k].z * ws; a1.w += u[k].w * ws;
              }
            }
          }
        }
      }
    }
    for (; j < e1; ++j) {
      int s = csr_src[j];
      float ws = 1.f;
      if constexpr (GNORM) ws = out_norm[s];
      const float4* p = h4 + (size_t)s * NF4;
      float4 v = p[lane];
      a0.x += v.x * ws; a0.y += v.y * ws; a0.z += v.z * ws; a0.w += v.w * ws;
      if constexpr (NF4 > 64) {
        if (hi) {
          float4 u = p[64 + lane];
          a1.x += u.x * ws; a1.y += u.y * ws; a1.z += u.z * ws; a1.w += u.w * ws;
        }
      }
    }
    float innm = in_norm[n];
    a0.x = (a0.x + c0.x) * innm; a0.y = (a0.y + c0.y) * innm;
    a0.z = (a0.z + c0.z) * innm; a0.w = (a0.w + c0.w) * innm;
    a1.x = (a1.x + c1.x) * innm; a1.y = (a1.y + c1.y) * innm;
    a1.z = (a1.z + c1.z) * innm; a1.w = (a1.w + c1.w) * innm;
    // store to LDS (linear element el -> layout address)
    {
      int el = lane * 4;
      float* dst0;
      if constexpr (IT_LAYOUT) dst0 = &agg[el];
      else { int t = el / F_IN; int i = el - t * F_IN; dst0 = &agg[t * RS + i]; }
      *(float4*)dst0 = a0;
      if constexpr (NF4 > 64) {
        if (hi) {
          int el1 = (64 + lane) * 4;
          float* dst1;
          if constexpr (IT_LAYOUT) dst1 = &agg[el1];
          else { int t = el1 / F_IN; int i = el1 - t * F_IN; dst1 = &agg[t * RS + i]; }
          *(float4*)dst1 = a1;
        }
      }
    }
  }
  __syncthreads();

  if (valid) {
    constexpr int G = F_OUT / 8;  // 5 or 8
    int t = lane >> 3, og = lane & 7;
    float acc[G];
    if constexpr (G == 8) {
      float4 bA = *(const float4*)&bias[og * 8];
      float4 bB = *(const float4*)&bias[og * 8 + 4];
      acc[0] = bA.x; acc[1] = bA.y; acc[2] = bA.z; acc[3] = bA.w;
      acc[4] = bB.x; acc[5] = bB.y; acc[6] = bB.z; acc[7] = bB.w;
    } else {
#pragma unroll
      for (int c = 0; c < G; ++c) acc[c] = bias[og * G + c];
    }
#pragma unroll 4
    for (int i = 0; i < F_IN; ++i) {
      float a;
      if constexpr (IT_LAYOUT) a = agg[i * 8 + t];
      else a = agg[t * RS + i];
      if constexpr (G == 8) {
        float4 wA = *(const float4*)&W[i * F_OUT + og * 8];
        float4 wB = *(const float4*)&W[i * F_OUT + og * 8 + 4];
        acc[0] += a * wA.x; acc[1] += a * wA.y; acc[2] += a * wA.z; acc[3] += a * wA.w;
        acc[4] += a * wB.x; acc[5] += a * wB.y; acc[6] += a * wB.z; acc[7] += a * wB.w;
      } else {
#pragma unroll
        for (int c = 0; c < G; ++c) acc[c] += a * W[i * F_OUT + og * G + c];
      }
    }
    float osc = 1.f;
    if constexpr (SCALE_OUT) osc = out_norm[n];
    float* orow = h_out + (size_t)n * (F_OUT * 8) + t * F_OUT + og * G;
#pragma unroll
    for (int c = 0; c < G; ++c) {
      float v = acc[c];
      if constexpr (RELU) v = fmaxf(v, 0.f);
      acc[c] = v * osc;
    }
    if constexpr (G == 8) {
      *(float4*)&orow[0] = make_float4(acc[0], acc[1], acc[2], acc[3]);
      *(float4*)&orow[4] = make_float4(acc[4], acc[5], acc[6], acc[7]);
    } else {
#pragma unroll
      for (int c = 0; c < G; ++c) orow[c] = acc[c];
    }
  }
}

// ---------------- temporal conv1d (k=3, pad=1) ----------------
#define CONV_NPW 8
__global__ __launch_bounds__(256) void conv_kernel(const float* h3, const float* __restrict__ Wc,
                                                   const float* __restrict__ bc, float* out, int N) {
  __shared__ float wc_t[192 * 64];      // [(i*3+k)*64 + o], 48 KB
  __shared__ float h3t[4][64 * 12];     // per-wave, [i*12 + t]
  int tid = threadIdx.x, lane = tid & 63, wave = tid >> 6;

  for (int m4 = tid; m4 < 3072; m4 += 256) {
    float4 v = ((const float4*)Wc)[m4];
    int m = m4 * 4;
    int o = m / 192, q = m % 192;
    wc_t[(q + 0) * 64 + o] = v.x;
    wc_t[(q + 1) * 64 + o] = v.y;
    wc_t[(q + 2) * 64 + o] = v.z;
    wc_t[(q + 3) * 64 + o] = v.w;
  }
  __syncthreads();
  float bo = bc[lane];
  float* ht = h3t[wave];

  for (int it = 0; it < CONV_NPW; ++it) {
    int n = blockIdx.x * (4 * CONV_NPW) + it * 4 + wave;
    bool valid = (n < N);
    if (valid) {
      const float* srcp = &h3[(size_t)n * 512];
#pragma unroll
      for (int r = 0; r < 8; ++r) ht[lane * 12 + r] = srcp[r * 64 + lane];
    }
    __syncthreads();
    if (valid) {
      float acc[8];
#pragma unroll
      for (int t = 0; t < 8; ++t) acc[t] = bo;
#pragma unroll 4
      for (int i = 0; i < 64; ++i) {
        float4 hA = *(const float4*)&ht[i * 12];
        float4 hB = *(const float4*)&ht[i * 12 + 4];
        float w0 = wc_t[(i * 3 + 0) * 64 + lane];
        float w1 = wc_t[(i * 3 + 1) * 64 + lane];
        float w2 = wc_t[(i * 3 + 2) * 64 + lane];
        float h[8] = {hA.x, hA.y, hA.z, hA.w, hB.x, hB.y, hB.z, hB.w};
#pragma unroll
        for (int t = 0; t < 8; ++t) acc[t] += w1 * h[t];
#pragma unroll
        for (int t = 1; t < 8; ++t) acc[t] += w0 * h[t - 1];
#pragma unroll
        for (int t = 0; t < 7; ++t) acc[t] += w2 * h[t + 1];
      }
      float4 r0 = make_float4(acc[0], acc[1], acc[2], acc[3]);
      float4 r1 = make_float4(acc[4], acc[5], acc[6], acc[7]);
      float4* dst = (float4*)&out[(size_t)n * 512 + lane * 8];
      dst[0] = r0;
      dst[1] = r1;
    }
    __syncthreads();
  }
}

// ---------------- launch ----------------

extern "C" void kernel_launch(void* const* d_in, const int* in_sizes, int n_in,
                              void* d_out, int out_size, void* d_ws, size_t ws_size,
                              hipStream_t stream) {
  const float* tf = (const float*)d_in[0];
  const int* src = (const int*)d_in[1];
  const int* dst = (const int*)d_in[2];
  const float* W1 = (const float*)d_in[3];
  const float* b1 = (const float*)d_in[4];
  const float* W2 = (const float*)d_in[5];
  const float* b2 = (const float*)d_in[6];
  const float* W3 = (const float*)d_in[7];
  const float* b3 = (const float*)d_in[8];
  const float* Wc = (const float*)d_in[9];
  const float* bc = (const float*)d_in[10];

  int N = in_sizes[0] / 256;  // [N, 32, 8]
  int E = in_sizes[1];

  char* ws = (char*)d_ws;
  size_t pos = 0;
  auto alloc = [&](size_t bytes) -> void* {
    void* p = ws + pos;
    pos += (bytes + 255) & ~(size_t)255;
    return p;
  };
  int* in_deg   = (int*)alloc((size_t)N * 4);
  int* out_deg  = (int*)alloc((size_t)N * 4);
  int* cursor   = (int*)alloc((size_t)N * 4);
  int* in_off   = (int*)alloc((size_t)(N + 1) * 4);
  int* partial  = (int*)alloc((size_t)1024 * 4);
  float* o_norm = (float*)alloc((size_t)N * 4);
  float* i_norm = (float*)alloc((size_t)N * 4);
  int* csr      = (int*)alloc((size_t)E * 4);
  float* h1     = (float*)alloc((size_t)N * 320 * 4);
  float* h2     = (float*)alloc((size_t)N * 512 * 4);
  float* h3     = (float*)d_out;  // reuse d_out as h3 storage (conv is node-local)

  hipMemsetAsync(in_deg, 0, (size_t)((char*)in_off - (char*)in_deg), stream);

  deg_kernel<<<(E + 255) / 256, 256, 0, stream>>>(src, dst, out_deg, in_deg, E);
  norm_kernel<<<(N + 255) / 256, 256, 0, stream>>>(out_deg, in_deg, o_norm, i_norm, N);

  int P = (N + 1023) / 1024;
  scan_partial_kernel<<<P, 256, 0, stream>>>(in_deg, partial, N);
  scan_partials_kernel<<<1, 1024, 0, stream>>>(partial, P);
  scan_apply_kernel<<<P, 1024, 0, stream>>>(in_deg, partial, in_off, N);

  scatter_kernel<<<(E + 255) / 256, 256, 0, stream>>>(src, dst, in_off, cursor, csr, E);

  int lg = (N + 3) / 4;
  // layer1: reads raw tf (needs out_norm in gather), writes h1 pre-scaled by out_norm
  layer_kernel<32, 40, 0, true, true, true, true, 8><<<lg, 256, 0, stream>>>(
      tf, csr, in_off, o_norm, i_norm, W1, b1, h1, N);
  // layer2: h1 already pre-scaled, writes h2 pre-scaled
  layer_kernel<40, 64, 40, false, true, false, true, 8><<<lg, 256, 0, stream>>>(
      h1, csr, in_off, o_norm, i_norm, W2, b2, h2, N);
  // layer3: h2 already pre-scaled, final output unscaled
  layer_kernel<64, 64, 72, false, false, false, false, 8><<<lg, 256, 0, stream>>>(
      h2, csr, in_off, o_norm, i_norm, W3, b3, h3, N);

  conv_kernel<<<(N + 4 * CONV_NPW - 1) / (4 * CONV_NPW), 256, 0, stream>>>(
      h3, Wc, bc, (float*)d_out, N);
}

// Round 4
// 1037.384 us; speedup vs baseline: 1.0914x; 1.0914x over previous
//
#include <hip/hip_runtime.h>

// ---------------- setup kernels ----------------

__global__ __launch_bounds__(256) void deg_kernel(const int* __restrict__ src,
                                                  const int* __restrict__ dst,
                                                  int* __restrict__ out_deg,
                                                  int* __restrict__ in_deg, int E) {
  int e = blockIdx.x * 256 + threadIdx.x;
  if (e < E) {
    atomicAdd(&out_deg[src[e]], 1);
    atomicAdd(&in_deg[dst[e]], 1);
  }
}

__global__ __launch_bounds__(256) void norm_kernel(const int* __restrict__ out_deg,
                                                   const int* __restrict__ in_deg,
                                                   float* __restrict__ out_norm,
                                                   float* __restrict__ in_norm, int N) {
  int n = blockIdx.x * 256 + threadIdx.x;
  if (n < N) {
    out_norm[n] = 1.0f / sqrtf((float)max(out_deg[n], 1));
    in_norm[n]  = 1.0f / sqrtf((float)max(in_deg[n], 1));
  }
}

// ---- parallel exclusive scan over N ints ----

__global__ __launch_bounds__(256) void scan_partial_kernel(const int* __restrict__ deg,
                                                           int* __restrict__ partial, int N) {
  __shared__ int ws[4];
  int tid = threadIdx.x, lane = tid & 63, wv = tid >> 6;
  int base = blockIdx.x * 1024;
  int v = 0;
#pragma unroll
  for (int k = 0; k < 4; ++k) {
    int i = base + tid + k * 256;
    if (i < N) v += deg[i];
  }
  for (int d = 32; d > 0; d >>= 1) v += __shfl_down(v, d, 64);
  if (lane == 0) ws[wv] = v;
  __syncthreads();
  if (tid == 0) partial[blockIdx.x] = ws[0] + ws[1] + ws[2] + ws[3];
}

__global__ __launch_bounds__(1024) void scan_partials_kernel(int* __restrict__ partial, int P) {
  __shared__ int wsum[16];
  int tid = threadIdx.x, lane = tid & 63, wv = tid >> 6;
  int v = (tid < P) ? partial[tid] : 0;
  int x = v;
  for (int d = 1; d < 64; d <<= 1) {
    int y = __shfl_up(x, d, 64);
    if (lane >= d) x += y;
  }
  if (lane == 63) wsum[wv] = x;
  __syncthreads();
  if (wv == 0 && lane < 16) {
    int y = wsum[lane];
    int z = y;
    for (int d = 1; d < 16; d <<= 1) {
      int q = __shfl_up(z, d, 64);
      if (lane >= d) z += q;
    }
    wsum[lane] = z - y;
  }
  __syncthreads();
  if (tid < P) partial[tid] = wsum[wv] + x - v;  // exclusive
}

__global__ __launch_bounds__(1024) void scan_apply_kernel(const int* __restrict__ deg,
                                                          const int* __restrict__ partial,
                                                          int* __restrict__ off, int N) {
  __shared__ int wsum[16];
  int tid = threadIdx.x, lane = tid & 63, wv = tid >> 6;
  int i = blockIdx.x * 1024 + tid;
  int v = (i < N) ? deg[i] : 0;
  int x = v;
  for (int d = 1; d < 64; d <<= 1) {
    int y = __shfl_up(x, d, 64);
    if (lane >= d) x += y;
  }
  if (lane == 63) wsum[wv] = x;
  __syncthreads();
  if (wv == 0 && lane < 16) {
    int y = wsum[lane];
    int z = y;
    for (int d = 1; d < 16; d <<= 1) {
      int q = __shfl_up(z, d, 64);
      if (lane >= d) z += q;
    }
    wsum[lane] = z - y;
  }
  __syncthreads();
  int excl = partial[blockIdx.x] + wsum[wv] + (x - v);
  if (i < N) off[i] = excl;
  if (i == N - 1) off[N] = excl + v;
}

__global__ __launch_bounds__(256) void scatter_kernel(const int* __restrict__ src,
                                                      const int* __restrict__ dst,
                                                      const int* __restrict__ in_off,
                                                      int* __restrict__ cursor,
                                                      int* __restrict__ csr_src, int E) {
  int e = blockIdx.x * 256 + threadIdx.x;
  if (e < E) {
    int d = dst[e];
    int p = atomicAdd(&cursor[d], 1);
    csr_src[in_off[d] + p] = src[e];
  }
}

// ---------------- graph-conv layer: quarter-wave gather ----------------
// Each node is handled by a QUARTER-wave (16 lanes): a wave carries 4
// independent edge streams -> 4x memory-level parallelism by SIMT structure
// (no compiler-fragile register batching). Lane r of quarter q covers chunks
// r + 16*k (float4) of its node's feature block; per iteration the wave has
// NC loads x 4 scattered 256B segments in flight. Block = 4 waves = 16 nodes.
// Gather result -> per-slot LDS (linear store, padded t-stride on read),
// then per-wave matmul over its own 4 slots (W row reused across 4 nodes).
template <int F_IN, int F_OUT, int TS, bool IT_LAYOUT, bool RELU, bool GNORM, bool SCALE_OUT>
__device__ __forceinline__ void layer_body(
    const float* __restrict__ h_in, const int* __restrict__ csr_src,
    const int* __restrict__ in_off, const float* __restrict__ out_norm,
    const float* __restrict__ in_norm, const float* __restrict__ W,
    const float* __restrict__ bias, float* __restrict__ h_out, int N) {
  constexpr int NF4 = F_IN * 8 / 4;   // float4 per node block: 64 / 80 / 128
  constexpr int NC = NF4 / 16;        // float4 per lane per edge: 4 / 5 / 8
  constexpr int SLOT = IT_LAYOUT ? F_IN * 8 : TS * 8;
  __shared__ float agg[16][SLOT];
  int tid = threadIdx.x;
  int wave = tid >> 6, lane = tid & 63;
  int q = lane >> 4, r = lane & 15;
  int slot = wave * 4 + q;
  int n = blockIdx.x * 16 + slot;
  bool valid = (n < N);

  float4 acc[NC];
#pragma unroll
  for (int k = 0; k < NC; ++k) acc[k] = make_float4(0.f, 0.f, 0.f, 0.f);

  if (valid) {
    int e0 = in_off[n], e1 = in_off[n + 1];
    const float4* h4 = (const float4*)h_in;
    int s_next = (e0 < e1) ? csr_src[e0] : 0;
    for (int j = e0; j < e1; ++j) {
      int s = s_next;
      s_next = csr_src[min(j + 1, e1 - 1)];  // branchless prefetch
      float w = 1.f;
      if constexpr (GNORM) w = out_norm[s];
      const float4* p = h4 + (size_t)s * NF4 + r;
      float4 v[NC];
#pragma unroll
      for (int k = 0; k < NC; ++k) v[k] = p[k * 16];
#pragma unroll
      for (int k = 0; k < NC; ++k) {
        if constexpr (GNORM) {
          acc[k].x = fmaf(v[k].x, w, acc[k].x);
          acc[k].y = fmaf(v[k].y, w, acc[k].y);
          acc[k].z = fmaf(v[k].z, w, acc[k].z);
          acc[k].w = fmaf(v[k].w, w, acc[k].w);
        } else {
          acc[k].x += v[k].x; acc[k].y += v[k].y;
          acc[k].z += v[k].z; acc[k].w += v[k].w;
        }
      }
    }
    float innm = in_norm[n];
#pragma unroll
    for (int k = 0; k < NC; ++k) {
      int el = k * 64 + r * 4;
      int addr;
      if constexpr (IT_LAYOUT) {
        addr = el;  // [f][t] linear
      } else {
        int t = el / F_IN;
        int i = el - t * F_IN;
        addr = t * TS + i;  // padded t-stride
      }
      *(float4*)&agg[slot][addr] = make_float4(acc[k].x * innm, acc[k].y * innm,
                                               acc[k].z * innm, acc[k].w * innm);
    }
  }
  __syncthreads();

  // matmul: wave processes its own 4 slots; W row loaded once, used 4x
  constexpr int G = F_OUT / 8;  // 5 or 8
  int t = lane >> 3, og = lane & 7;
  float acc2[4][G];
  {
    float bb[G];
    if constexpr (G == 8) {
      float4 bA = *(const float4*)&bias[og * 8];
      float4 bB = *(const float4*)&bias[og * 8 + 4];
      bb[0] = bA.x; bb[1] = bA.y; bb[2] = bA.z; bb[3] = bA.w;
      bb[4] = bB.x; bb[5] = bB.y; bb[6] = bB.z; bb[7] = bB.w;
    } else {
#pragma unroll
      for (int c = 0; c < G; ++c) bb[c] = bias[og * G + c];
    }
#pragma unroll
    for (int qq = 0; qq < 4; ++qq)
#pragma unroll
      for (int c = 0; c < G; ++c) acc2[qq][c] = bb[c];
  }
#pragma unroll 4
  for (int i = 0; i < F_IN; ++i) {
    float wrow[G];
    if constexpr (G == 8) {
      float4 wA = *(const float4*)&W[i * F_OUT + og * 8];
      float4 wB = *(const float4*)&W[i * F_OUT + og * 8 + 4];
      wrow[0] = wA.x; wrow[1] = wA.y; wrow[2] = wA.z; wrow[3] = wA.w;
      wrow[4] = wB.x; wrow[5] = wB.y; wrow[6] = wB.z; wrow[7] = wB.w;
    } else {
#pragma unroll
      for (int c = 0; c < G; ++c) wrow[c] = W[i * F_OUT + og * G + c];
    }
    int raddr;
    if constexpr (IT_LAYOUT) raddr = i * 8 + t;
    else raddr = t * TS + i;
#pragma unroll
    for (int qq = 0; qq < 4; ++qq) {
      float a = agg[wave * 4 + qq][raddr];
#pragma unroll
      for (int c = 0; c < G; ++c) acc2[qq][c] = fmaf(a, wrow[c], acc2[qq][c]);
    }
  }
#pragma unroll
  for (int qq = 0; qq < 4; ++qq) {
    int n2 = blockIdx.x * 16 + wave * 4 + qq;
    if (n2 < N) {
      float osc = 1.f;
      if constexpr (SCALE_OUT) osc = out_norm[n2];
      float* orow = h_out + (size_t)n2 * (F_OUT * 8) + t * F_OUT + og * G;
      float res[G];
#pragma unroll
      for (int c = 0; c < G; ++c) {
        float v = acc2[qq][c];
        if constexpr (RELU) v = fmaxf(v, 0.f);
        res[c] = v * osc;
      }
      if constexpr (G == 8) {
        *(float4*)&orow[0] = make_float4(res[0], res[1], res[2], res[3]);
        *(float4*)&orow[4] = make_float4(res[4], res[5], res[6], res[7]);
      } else {
#pragma unroll
        for (int c = 0; c < G; ++c) orow[c] = res[c];
      }
    }
  }
}

__global__ __launch_bounds__(256) void layer1_k(
    const float* __restrict__ h_in, const int* __restrict__ csr_src,
    const int* __restrict__ in_off, const float* __restrict__ out_norm,
    const float* __restrict__ in_norm, const float* __restrict__ W,
    const float* __restrict__ bias, float* __restrict__ h_out, int N) {
  layer_body<32, 40, 0, true, true, true, true>(h_in, csr_src, in_off, out_norm,
                                                in_norm, W, bias, h_out, N);
}

__global__ __launch_bounds__(256) void layer2_k(
    const float* __restrict__ h_in, const int* __restrict__ csr_src,
    const int* __restrict__ in_off, const float* __restrict__ out_norm,
    const float* __restrict__ in_norm, const float* __restrict__ W,
    const float* __restrict__ bias, float* __restrict__ h_out, int N) {
  layer_body<40, 64, 44, false, true, false, true>(h_in, csr_src, in_off, out_norm,
                                                   in_norm, W, bias, h_out, N);
}

__global__ __launch_bounds__(256) void layer3_k(
    const float* __restrict__ h_in, const int* __restrict__ csr_src,
    const int* __restrict__ in_off, const float* __restrict__ out_norm,
    const float* __restrict__ in_norm, const float* __restrict__ W,
    const float* __restrict__ bias, float* __restrict__ h_out, int N) {
  layer_body<64, 64, 68, false, false, false, false>(h_in, csr_src, in_off, out_norm,
                                                     in_norm, W, bias, h_out, N);
}

// ---------------- temporal conv1d (k=3, pad=1) ----------------
#define CONV_NPW 8
__global__ __launch_bounds__(256) void conv_kernel(const float* h3, const float* __restrict__ Wc,
                                                   const float* __restrict__ bc, float* out, int N) {
  __shared__ float wc_t[192 * 64];      // [(i*3+k)*64 + o], 48 KB
  __shared__ float h3t[4][64 * 12];     // per-wave, [i*12 + t]
  int tid = threadIdx.x, lane = tid & 63, wave = tid >> 6;

  for (int m4 = tid; m4 < 3072; m4 += 256) {
    float4 v = ((const float4*)Wc)[m4];
    int m = m4 * 4;
    int o = m / 192, q = m % 192;
    wc_t[(q + 0) * 64 + o] = v.x;
    wc_t[(q + 1) * 64 + o] = v.y;
    wc_t[(q + 2) * 64 + o] = v.z;
    wc_t[(q + 3) * 64 + o] = v.w;
  }
  __syncthreads();
  float bo = bc[lane];
  float* ht = h3t[wave];

  for (int it = 0; it < CONV_NPW; ++it) {
    int n = blockIdx.x * (4 * CONV_NPW) + it * 4 + wave;
    bool valid = (n < N);
    if (valid) {
      const float* srcp = &h3[(size_t)n * 512];
#pragma unroll
      for (int r = 0; r < 8; ++r) ht[lane * 12 + r] = srcp[r * 64 + lane];
    }
    __syncthreads();
    if (valid) {
      float acc[8];
#pragma unroll
      for (int t = 0; t < 8; ++t) acc[t] = bo;
#pragma unroll 4
      for (int i = 0; i < 64; ++i) {
        float4 hA = *(const float4*)&ht[i * 12];
        float4 hB = *(const float4*)&ht[i * 12 + 4];
        float w0 = wc_t[(i * 3 + 0) * 64 + lane];
        float w1 = wc_t[(i * 3 + 1) * 64 + lane];
        float w2 = wc_t[(i * 3 + 2) * 64 + lane];
        float h[8] = {hA.x, hA.y, hA.z, hA.w, hB.x, hB.y, hB.z, hB.w};
#pragma unroll
        for (int t = 0; t < 8; ++t) acc[t] += w1 * h[t];
#pragma unroll
        for (int t = 1; t < 8; ++t) acc[t] += w0 * h[t - 1];
#pragma unroll
        for (int t = 0; t < 7; ++t) acc[t] += w2 * h[t + 1];
      }
      float4 r0 = make_float4(acc[0], acc[1], acc[2], acc[3]);
      float4 r1 = make_float4(acc[4], acc[5], acc[6], acc[7]);
      float4* dst = (float4*)&out[(size_t)n * 512 + lane * 8];
      dst[0] = r0;
      dst[1] = r1;
    }
    __syncthreads();
  }
}

// ---------------- launch ----------------

extern "C" void kernel_launch(void* const* d_in, const int* in_sizes, int n_in,
                              void* d_out, int out_size, void* d_ws, size_t ws_size,
                              hipStream_t stream) {
  const float* tf = (const float*)d_in[0];
  const int* src = (const int*)d_in[1];
  const int* dst = (const int*)d_in[2];
  const float* W1 = (const float*)d_in[3];
  const float* b1 = (const float*)d_in[4];
  const float* W2 = (const float*)d_in[5];
  const float* b2 = (const float*)d_in[6];
  const float* W3 = (const float*)d_in[7];
  const float* b3 = (const float*)d_in[8];
  const float* Wc = (const float*)d_in[9];
  const float* bc = (const float*)d_in[10];

  int N = in_sizes[0] / 256;  // [N, 32, 8]
  int E = in_sizes[1];

  char* ws = (char*)d_ws;
  size_t pos = 0;
  auto alloc = [&](size_t bytes) -> void* {
    void* p = ws + pos;
    pos += (bytes + 255) & ~(size_t)255;
    return p;
  };
  int* in_deg   = (int*)alloc((size_t)N * 4);
  int* out_deg  = (int*)alloc((size_t)N * 4);
  int* cursor   = (int*)alloc((size_t)N * 4);
  int* in_off   = (int*)alloc((size_t)(N + 1) * 4);
  int* partial  = (int*)alloc((size_t)1024 * 4);
  float* o_norm = (float*)alloc((size_t)N * 4);
  float* i_norm = (float*)alloc((size_t)N * 4);
  int* csr      = (int*)alloc((size_t)E * 4);
  float* h1     = (float*)alloc((size_t)N * 320 * 4);
  float* h2     = (float*)alloc((size_t)N * 512 * 4);
  float* h3     = (float*)d_out;  // reuse d_out as h3 storage (conv is node-local)

  hipMemsetAsync(in_deg, 0, (size_t)((char*)in_off - (char*)in_deg), stream);

  deg_kernel<<<(E + 255) / 256, 256, 0, stream>>>(src, dst, out_deg, in_deg, E);
  norm_kernel<<<(N + 255) / 256, 256, 0, stream>>>(out_deg, in_deg, o_norm, i_norm, N);

  int P = (N + 1023) / 1024;
  scan_partial_kernel<<<P, 256, 0, stream>>>(in_deg, partial, N);
  scan_partials_kernel<<<1, 1024, 0, stream>>>(partial, P);
  scan_apply_kernel<<<P, 1024, 0, stream>>>(in_deg, partial, in_off, N);

  scatter_kernel<<<(E + 255) / 256, 256, 0, stream>>>(src, dst, in_off, cursor, csr, E);

  int lg = (N + 15) / 16;
  // layer1: reads raw tf (needs out_norm in gather), writes h1 pre-scaled by out_norm
  layer1_k<<<lg, 256, 0, stream>>>(tf, csr, in_off, o_norm, i_norm, W1, b1, h1, N);
  // layer2: h1 already pre-scaled, writes h2 pre-scaled
  layer2_k<<<lg, 256, 0, stream>>>(h1, csr, in_off, o_norm, i_norm, W2, b2, h2, N);
  // layer3: h2 already pre-scaled, final output unscaled
  layer3_k<<<lg, 256, 0, stream>>>(h2, csr, in_off, o_norm, i_norm, W3, b3, h3, N);

  conv_kernel<<<(N + 4 * CONV_NPW - 1) / (4 * CONV_NPW), 256, 0, stream>>>(
      h3, Wc, bc, (float*)d_out, N);
}

// Round 5
// 915.947 us; speedup vs baseline: 1.2361x; 1.1326x over previous
//
#include <hip/hip_runtime.h>

// ---------------- setup kernels ----------------

__global__ __launch_bounds__(256) void deg_kernel(const int* __restrict__ src,
                                                  const int* __restrict__ dst,
                                                  int* __restrict__ out_deg,
                                                  int* __restrict__ in_deg, int E) {
  int e = blockIdx.x * 256 + threadIdx.x;
  if (e < E) {
    atomicAdd(&out_deg[src[e]], 1);
    atomicAdd(&in_deg[dst[e]], 1);
  }
}

__global__ __launch_bounds__(256) void norm_kernel(const int* __restrict__ out_deg,
                                                   const int* __restrict__ in_deg,
                                                   float* __restrict__ out_norm,
                                                   float* __restrict__ in_norm, int N) {
  int n = blockIdx.x * 256 + threadIdx.x;
  if (n < N) {
    out_norm[n] = 1.0f / sqrtf((float)max(out_deg[n], 1));
    in_norm[n]  = 1.0f / sqrtf((float)max(in_deg[n], 1));
  }
}

// transpose Wc[o][i][k] -> wct[(i*3+k)*64 + o]  (12288 floats)
__global__ __launch_bounds__(256) void wct_kernel(const float* __restrict__ Wc,
                                                  float* __restrict__ wct) {
  int m = blockIdx.x * 256 + threadIdx.x;
  if (m < 12288) wct[m] = Wc[(m & 63) * 192 + (m >> 6)];
}

// ---- parallel exclusive scan over N ints ----

__global__ __launch_bounds__(256) void scan_partial_kernel(const int* __restrict__ deg,
                                                           int* __restrict__ partial, int N) {
  __shared__ int ws[4];
  int tid = threadIdx.x, lane = tid & 63, wv = tid >> 6;
  int base = blockIdx.x * 1024;
  int v = 0;
#pragma unroll
  for (int k = 0; k < 4; ++k) {
    int i = base + tid + k * 256;
    if (i < N) v += deg[i];
  }
  for (int d = 32; d > 0; d >>= 1) v += __shfl_down(v, d, 64);
  if (lane == 0) ws[wv] = v;
  __syncthreads();
  if (tid == 0) partial[blockIdx.x] = ws[0] + ws[1] + ws[2] + ws[3];
}

__global__ __launch_bounds__(1024) void scan_partials_kernel(int* __restrict__ partial, int P) {
  __shared__ int wsum[16];
  int tid = threadIdx.x, lane = tid & 63, wv = tid >> 6;
  int v = (tid < P) ? partial[tid] : 0;
  int x = v;
  for (int d = 1; d < 64; d <<= 1) {
    int y = __shfl_up(x, d, 64);
    if (lane >= d) x += y;
  }
  if (lane == 63) wsum[wv] = x;
  __syncthreads();
  if (wv == 0 && lane < 16) {
    int y = wsum[lane];
    int z = y;
    for (int d = 1; d < 16; d <<= 1) {
      int q = __shfl_up(z, d, 64);
      if (lane >= d) z += q;
    }
    wsum[lane] = z - y;
  }
  __syncthreads();
  if (tid < P) partial[tid] = wsum[wv] + x - v;  // exclusive
}

__global__ __launch_bounds__(1024) void scan_apply_kernel(const int* __restrict__ deg,
                                                          const int* __restrict__ partial,
                                                          int* __restrict__ off, int N) {
  __shared__ int wsum[16];
  int tid = threadIdx.x, lane = tid & 63, wv = tid >> 6;
  int i = blockIdx.x * 1024 + tid;
  int v = (i < N) ? deg[i] : 0;
  int x = v;
  for (int d = 1; d < 64; d <<= 1) {
    int y = __shfl_up(x, d, 64);
    if (lane >= d) x += y;
  }
  if (lane == 63) wsum[wv] = x;
  __syncthreads();
  if (wv == 0 && lane < 16) {
    int y = wsum[lane];
    int z = y;
    for (int d = 1; d < 16; d <<= 1) {
      int q = __shfl_up(z, d, 64);
      if (lane >= d) z += q;
    }
    wsum[lane] = z - y;
  }
  __syncthreads();
  int excl = partial[blockIdx.x] + wsum[wv] + (x - v);
  if (i < N) off[i] = excl;
  if (i == N - 1) off[N] = excl + v;
}

__global__ __launch_bounds__(256) void scatter_kernel(const int* __restrict__ src,
                                                      const int* __restrict__ dst,
                                                      const int* __restrict__ in_off,
                                                      int* __restrict__ cursor,
                                                      int* __restrict__ csr_src, int E) {
  int e = blockIdx.x * 256 + threadIdx.x;
  if (e < E) {
    int d = dst[e];
    int p = atomicAdd(&cursor[d], 1);
    csr_src[in_off[d] + p] = src[e];
  }
}

// ---------------- graph-conv layer: L-lane-per-node gather ----------------
// Each node handled by L lanes (L=8 for layer1, 16 for layers 2/3): a wave
// carries 64/L independent edge streams. 2-edge unroll doubles loads in
// flight per stream. Gather -> per-slot LDS (slot stride padded +8 floats so
// concurrent q-groups hit different banks), then per-wave matmul over its
// M=64/L slots (W row reused across M nodes).
// TSTORE: write output transposed as [n][i][t] (for conv); else [n][t][o].
template <int F_IN, int F_OUT, int TS, int L, bool IT_LAYOUT, bool RELU,
          bool GNORM, bool SCALE_OUT, bool TSTORE>
__device__ __forceinline__ void layer_body(
    const float* __restrict__ h_in, const int* __restrict__ csr_src,
    const int* __restrict__ in_off, const float* __restrict__ out_norm,
    const float* __restrict__ in_norm, const float* __restrict__ W,
    const float* __restrict__ bias, float* __restrict__ h_out, int N) {
  constexpr int NF4 = F_IN * 2;       // float4 per node block: 64 / 80 / 128
  constexpr int NC = NF4 / L;         // float4 per lane per edge
  constexpr int M = 64 / L;           // nodes per wave
  constexpr int SLOTS = 4 * M;        // nodes per block
  constexpr int SLOT = (IT_LAYOUT ? F_IN * 8 : TS * 8) + 8;  // +8: bank stagger
  __shared__ float agg[SLOTS][SLOT];
  int tid = threadIdx.x;
  int wave = tid >> 6, lane = tid & 63;
  int q = lane / L, r = lane % L;
  int slot = wave * M + q;
  int n = blockIdx.x * SLOTS + slot;
  bool valid = (n < N);

  float4 acc[NC];
#pragma unroll
  for (int k = 0; k < NC; ++k) acc[k] = make_float4(0.f, 0.f, 0.f, 0.f);

  if (valid) {
    int e0 = in_off[n], e1 = in_off[n + 1];
    const float4* h4 = (const float4*)h_in;
    int j = e0;
    if (e1 - e0 >= 2) {
      int sA = csr_src[j], sB = csr_src[j + 1];
      do {
        int cA = sA, cB = sB;
        int jn = j + 2;
        sA = csr_src[min(jn, e1 - 1)];       // branchless prefetch
        sB = csr_src[min(jn + 1, e1 - 1)];
        float wA = 1.f, wB = 1.f;
        if constexpr (GNORM) { wA = out_norm[cA]; wB = out_norm[cB]; }
        const float4* pA = h4 + (size_t)cA * NF4 + r;
        const float4* pB = h4 + (size_t)cB * NF4 + r;
        float4 vA[NC], vB[NC];
#pragma unroll
        for (int k = 0; k < NC; ++k) vA[k] = pA[k * L];
#pragma unroll
        for (int k = 0; k < NC; ++k) vB[k] = pB[k * L];
#pragma unroll
        for (int k = 0; k < NC; ++k) {
          acc[k].x = fmaf(vA[k].x, wA, acc[k].x);
          acc[k].y = fmaf(vA[k].y, wA, acc[k].y);
          acc[k].z = fmaf(vA[k].z, wA, acc[k].z);
          acc[k].w = fmaf(vA[k].w, wA, acc[k].w);
          acc[k].x = fmaf(vB[k].x, wB, acc[k].x);
          acc[k].y = fmaf(vB[k].y, wB, acc[k].y);
          acc[k].z = fmaf(vB[k].z, wB, acc[k].z);
          acc[k].w = fmaf(vB[k].w, wB, acc[k].w);
        }
        j = jn;
      } while (j + 2 <= e1);
    }
    if (j < e1) {  // at most one tail edge
      int s = csr_src[j];
      float w = 1.f;
      if constexpr (GNORM) w = out_norm[s];
      const float4* p = h4 + (size_t)s * NF4 + r;
#pragma unroll
      for (int k = 0; k < NC; ++k) {
        float4 v = p[k * L];
        acc[k].x = fmaf(v.x, w, acc[k].x);
        acc[k].y = fmaf(v.y, w, acc[k].y);
        acc[k].z = fmaf(v.z, w, acc[k].z);
        acc[k].w = fmaf(v.w, w, acc[k].w);
      }
    }
    float innm = in_norm[n];
#pragma unroll
    for (int k = 0; k < NC; ++k) {
      int el = (k * L + r) * 4;
      int addr;
      if constexpr (IT_LAYOUT) {
        addr = el;  // [f][t] linear
      } else {
        int t = el / F_IN;
        int i = el - t * F_IN;
        addr = t * TS + i;  // padded t-stride
      }
      *(float4*)&agg[slot][addr] = make_float4(acc[k].x * innm, acc[k].y * innm,
                                               acc[k].z * innm, acc[k].w * innm);
    }
  }
  __syncthreads();

  // matmul: wave processes its own M slots; W row loaded once, used M times
  constexpr int G = F_OUT / 8;  // 5 or 8
  int t = lane >> 3, og = lane & 7;
  float acc2[M][G];
  {
    float bb[G];
    if constexpr (G == 8) {
      float4 bA = *(const float4*)&bias[og * 8];
      float4 bB = *(const float4*)&bias[og * 8 + 4];
      bb[0] = bA.x; bb[1] = bA.y; bb[2] = bA.z; bb[3] = bA.w;
      bb[4] = bB.x; bb[5] = bB.y; bb[6] = bB.z; bb[7] = bB.w;
    } else {
#pragma unroll
      for (int c = 0; c < G; ++c) bb[c] = bias[og * G + c];
    }
#pragma unroll
    for (int qq = 0; qq < M; ++qq)
#pragma unroll
      for (int c = 0; c < G; ++c) acc2[qq][c] = bb[c];
  }
#pragma unroll 4
  for (int i = 0; i < F_IN; ++i) {
    float wrow[G];
    if constexpr (G == 8) {
      float4 wA = *(const float4*)&W[i * F_OUT + og * 8];
      float4 wB = *(const float4*)&W[i * F_OUT + og * 8 + 4];
      wrow[0] = wA.x; wrow[1] = wA.y; wrow[2] = wA.z; wrow[3] = wA.w;
      wrow[4] = wB.x; wrow[5] = wB.y; wrow[6] = wB.z; wrow[7] = wB.w;
    } else {
#pragma unroll
      for (int c = 0; c < G; ++c) wrow[c] = W[i * F_OUT + og * G + c];
    }
    int raddr;
    if constexpr (IT_LAYOUT) raddr = i * 8 + t;
    else raddr = t * TS + i;
#pragma unroll
    for (int qq = 0; qq < M; ++qq) {
      float a = agg[wave * M + qq][raddr];
#pragma unroll
      for (int c = 0; c < G; ++c) acc2[qq][c] = fmaf(a, wrow[c], acc2[qq][c]);
    }
  }
#pragma unroll
  for (int qq = 0; qq < M; ++qq) {
    int n2 = blockIdx.x * SLOTS + wave * M + qq;
    if (n2 < N) {
      float osc = 1.f;
      if constexpr (SCALE_OUT) osc = out_norm[n2];
      float res[G];
#pragma unroll
      for (int c = 0; c < G; ++c) {
        float v = acc2[qq][c];
        if constexpr (RELU) v = fmaxf(v, 0.f);
        res[c] = v * osc;
      }
      if constexpr (TSTORE) {
        // element (t, o=og*8+c) -> [n][o][t] = n*512 + (og*8+c)*8 + t
        float* ob = h_out + (size_t)n2 * 512 + og * 64 + t;
#pragma unroll
        for (int c = 0; c < G; ++c) ob[c * 8] = res[c];
      } else {
        float* orow = h_out + (size_t)n2 * (F_OUT * 8) + t * F_OUT + og * G;
        if constexpr (G == 8) {
          *(float4*)&orow[0] = make_float4(res[0], res[1], res[2], res[3]);
          *(float4*)&orow[4] = make_float4(res[4], res[5], res[6], res[7]);
        } else {
#pragma unroll
          for (int c = 0; c < G; ++c) orow[c] = res[c];
        }
      }
    }
  }
}

__global__ __launch_bounds__(256) void layer1_k(
    const float* __restrict__ h_in, const int* __restrict__ csr_src,
    const int* __restrict__ in_off, const float* __restrict__ out_norm,
    const float* __restrict__ in_norm, const float* __restrict__ W,
    const float* __restrict__ bias, float* __restrict__ h_out, int N) {
  layer_body<32, 40, 0, 8, true, true, true, true, false>(
      h_in, csr_src, in_off, out_norm, in_norm, W, bias, h_out, N);
}

__global__ __launch_bounds__(256) void layer2_k(
    const float* __restrict__ h_in, const int* __restrict__ csr_src,
    const int* __restrict__ in_off, const float* __restrict__ out_norm,
    const float* __restrict__ in_norm, const float* __restrict__ W,
    const float* __restrict__ bias, float* __restrict__ h_out, int N) {
  layer_body<40, 64, 44, 16, false, true, false, true, false>(
      h_in, csr_src, in_off, out_norm, in_norm, W, bias, h_out, N);
}

__global__ __launch_bounds__(256) void layer3_k(
    const float* __restrict__ h_in, const int* __restrict__ csr_src,
    const int* __restrict__ in_off, const float* __restrict__ out_norm,
    const float* __restrict__ in_norm, const float* __restrict__ W,
    const float* __restrict__ bias, float* __restrict__ h_out, int N) {
  layer_body<64, 64, 68, 16, false, false, false, false, true>(
      h_in, csr_src, in_off, out_norm, in_norm, W, bias, h_out, N);
}

// ---------------- temporal conv1d (k=3, pad=1), quarter-wave per node -----
// h3 lives in d_out in [n][i][t] layout (written by layer3). Each 16-lane
// group owns one node's 4-channel slice: lane r computes o = r*4..r*4+3, all
// t. Weights read from pre-transposed GLOBAL wct[(i*3+k)*64+o] (L1/L2-hot,
// no 48KB LDS copy -> occupancy). h staged wave-privately in LDS: stride-1
// writes, broadcast reads, +4 float pad per node slot (516) staggers the 4
// q-groups across banks. No __syncthreads anywhere. In-place safe: all loads
// of the wave's region complete (feed acc) before any store issues.
__global__ __launch_bounds__(256) void conv_qn_kernel(const float* __restrict__ wct,
                                                      const float* __restrict__ bc,
                                                      float* dout, int N) {
  __shared__ float hlds[4][4 * 516];
  int tid = threadIdx.x, wave = tid >> 6, lane = tid & 63;
  int q = lane >> 4, r = lane & 15;
  int base = blockIdx.x * 16 + wave * 4;  // wave's first node
  float* hl = hlds[wave];

  // stage 4 nodes (2048 floats = 512 float4) cooperatively, stride-1 in LDS
  const float4* g4 = (const float4*)dout;
  long long wb4 = (long long)base * 128;
  long long lim = (long long)N * 128;
#pragma unroll
  for (int k = 0; k < 8; ++k) {
    long long F4 = wb4 + k * 64 + lane;
    float4 v = make_float4(0.f, 0.f, 0.f, 0.f);
    if (F4 < lim) v = g4[F4];
    int local = k * 64 + lane;
    int qp = local >> 7, rem = local & 127;
    *(float4*)&hl[qp * 516 + rem * 4] = v;
  }
  // wave-private: compiler's lgkmcnt ordering suffices, no barrier

  float4 b4 = *(const float4*)&bc[r * 4];
  float bcv[4] = {b4.x, b4.y, b4.z, b4.w};
  float acc[4][8];
#pragma unroll
  for (int c = 0; c < 4; ++c)
#pragma unroll
    for (int t = 0; t < 8; ++t) acc[c][t] = bcv[c];

  const float4* wct4 = (const float4*)wct;
  const float* hq = &hl[q * 516];
#pragma unroll 2
  for (int i = 0; i < 64; ++i) {
    float4 hA = *(const float4*)&hq[i * 8];
    float4 hB = *(const float4*)&hq[i * 8 + 4];
    float4 w0 = wct4[(i * 3 + 0) * 16 + r];
    float4 w1 = wct4[(i * 3 + 1) * 16 + r];
    float4 w2 = wct4[(i * 3 + 2) * 16 + r];
    float h[8] = {hA.x, hA.y, hA.z, hA.w, hB.x, hB.y, hB.z, hB.w};
    float wk0[4] = {w0.x, w0.y, w0.z, w0.w};
    float wk1[4] = {w1.x, w1.y, w1.z, w1.w};
    float wk2[4] = {w2.x, w2.y, w2.z, w2.w};
#pragma unroll
    for (int c = 0; c < 4; ++c) {
#pragma unroll
      for (int t = 0; t < 8; ++t) acc[c][t] = fmaf(wk1[c], h[t], acc[c][t]);
#pragma unroll
      for (int t = 1; t < 8; ++t) acc[c][t] = fmaf(wk0[c], h[t - 1], acc[c][t]);
#pragma unroll
      for (int t = 0; t < 7; ++t) acc[c][t] = fmaf(wk2[c], h[t + 1], acc[c][t]);
    }
  }
  int n = base + q;
  if (n < N) {
    float* ob = dout + (size_t)n * 512 + r * 32;  // o = r*4+c -> offset o*8
#pragma unroll
    for (int c = 0; c < 4; ++c) {
      *(float4*)&ob[c * 8] = make_float4(acc[c][0], acc[c][1], acc[c][2], acc[c][3]);
      *(float4*)&ob[c * 8 + 4] = make_float4(acc[c][4], acc[c][5], acc[c][6], acc[c][7]);
    }
  }
}

// ---------------- launch ----------------

extern "C" void kernel_launch(void* const* d_in, const int* in_sizes, int n_in,
                              void* d_out, int out_size, void* d_ws, size_t ws_size,
                              hipStream_t stream) {
  const float* tf = (const float*)d_in[0];
  const int* src = (const int*)d_in[1];
  const int* dst = (const int*)d_in[2];
  const float* W1 = (const float*)d_in[3];
  const float* b1 = (const float*)d_in[4];
  const float* W2 = (const float*)d_in[5];
  const float* b2 = (const float*)d_in[6];
  const float* W3 = (const float*)d_in[7];
  const float* b3 = (const float*)d_in[8];
  const float* Wc = (const float*)d_in[9];
  const float* bc = (const float*)d_in[10];

  int N = in_sizes[0] / 256;  // [N, 32, 8]
  int E = in_sizes[1];

  char* ws = (char*)d_ws;
  size_t pos = 0;
  auto alloc = [&](size_t bytes) -> void* {
    void* p = ws + pos;
    pos += (bytes + 255) & ~(size_t)255;
    return p;
  };
  int* in_deg   = (int*)alloc((size_t)N * 4);
  int* out_deg  = (int*)alloc((size_t)N * 4);
  int* cursor   = (int*)alloc((size_t)N * 4);
  int* in_off   = (int*)alloc((size_t)(N + 1) * 4);
  int* partial  = (int*)alloc((size_t)1024 * 4);
  float* o_norm = (float*)alloc((size_t)N * 4);
  float* i_norm = (float*)alloc((size_t)N * 4);
  int* csr      = (int*)alloc((size_t)E * 4);
  float* wct    = (float*)alloc((size_t)12288 * 4);
  float* h1     = (float*)alloc((size_t)N * 320 * 4);
  float* h2     = (float*)alloc((size_t)N * 512 * 4);
  float* h3     = (float*)d_out;  // h3 in [n][i][t] layout, conv is in-place

  hipMemsetAsync(in_deg, 0, (size_t)((char*)in_off - (char*)in_deg), stream);

  deg_kernel<<<(E + 255) / 256, 256, 0, stream>>>(src, dst, out_deg, in_deg, E);
  norm_kernel<<<(N + 255) / 256, 256, 0, stream>>>(out_deg, in_deg, o_norm, i_norm, N);
  wct_kernel<<<48, 256, 0, stream>>>(Wc, wct);

  int P = (N + 1023) / 1024;
  scan_partial_kernel<<<P, 256, 0, stream>>>(in_deg, partial, N);
  scan_partials_kernel<<<1, 1024, 0, stream>>>(partial, P);
  scan_apply_kernel<<<P, 1024, 0, stream>>>(in_deg, partial, in_off, N);

  scatter_kernel<<<(E + 255) / 256, 256, 0, stream>>>(src, dst, in_off, cursor, csr, E);

  // layer1: raw tf (out_norm in gather), 8-lane streams, 32 nodes/block
  layer1_k<<<(N + 31) / 32, 256, 0, stream>>>(tf, csr, in_off, o_norm, i_norm, W1, b1, h1, N);
  // layer2: pre-scaled input, writes pre-scaled, 16 nodes/block
  layer2_k<<<(N + 15) / 16, 256, 0, stream>>>(h1, csr, in_off, o_norm, i_norm, W2, b2, h2, N);
  // layer3: final, writes h3 transposed [n][i][t] into d_out
  layer3_k<<<(N + 15) / 16, 256, 0, stream>>>(h2, csr, in_off, o_norm, i_norm, W3, b3, h3, N);

  conv_qn_kernel<<<(N + 15) / 16, 256, 0, stream>>>(wct, bc, (float*)d_out, N);
}